// Round 13
// baseline (356.679 us; speedup 1.0000x reference)
//
#include <hip/hip_runtime.h>
#include <math.h>

#define NN 100000
#define EE 640000
#define GG 128
#define BN_EPS 1e-5f
#define NBLK 98  // ceil(NN/1024)

typedef __attribute__((ext_vector_type(8))) short short8;
typedef __attribute__((ext_vector_type(4))) float f32x4;

// ---------------- ws layout (byte offsets) ----------------
// Abf : [0,          25,600,000)   N x 128 bf16 (h0)
// Bbf : [25,600,000, 51,200,000)   N x 128 bf16 (h1)
// Z   : [51,200,000, 51,600,000)   N fp32
// SM  : [51,600,000, +16,448)      S0r(8x256) S1r(8x256) S2r(16)
// gb  : [51,616,448, +516)         129 int graph boundaries (start[g])
// offs: [51,620,000, +400,004)     N+1 int
// csr : [52,020,516, +2,560,000)
// Wt  : [54,580,544, +163,840)     5 x 128x128 bf16 (MFMA-fragment-ordered)
// Xbf : [54,744,384, +25,600,000)  N x 128 bf16 (x pre-rounded)
// deg/pos alias Abf region during CSR build (Abf not yet live).

__device__ __forceinline__ short f2bf(float f) {
    unsigned u = __float_as_uint(f);
    u += 0x7fffu + ((u >> 16) & 1);
    return (short)(u >> 16);
}
__device__ __forceinline__ float bf2f(short s) {
    return __uint_as_float(((unsigned)(unsigned short)s) << 16);
}
// XOR-swizzled LDS addressing (16B chunks), padding-free & ~conflict-free
__device__ __forceinline__ int swz(int row, int chunk) {
    return row * 128 + ((chunk ^ (row & 15)) << 3);
}
__device__ __forceinline__ int swze(int row, int col) {
    return row * 128 + (((col >> 3) ^ (row & 15)) << 3) + (col & 7);
}

// ---------------- fused prep ----------------
// x->bf16 + weights->fragment order + degree histogram + zero stats +
// graph-boundary table gb[g] (batch sorted; every g written exactly once).
// R11 lesson: launch boundaries are cheap under graph replay; small kernels'
// EXECUTION is the cost — fold cheap independent work here, never global-sync.
// Fragment order: value W[k][n] lands at
//   wi*16384 + (((ch*4+ct)*4+kk)*64 + lane)*8 + e
// ch=n>>6, ct=(n>>4)&3, r16=n&15, kc=k>>3, kk=kc>>2, q=kc&3,
// lane=r16+16*q, e=k&7  => a wave's B-fragment load is one contiguous 1KB.
__global__ void k_prep(const float* __restrict__ x,
                       const float* __restrict__ W0a, const float* __restrict__ W0b,
                       const float* __restrict__ W1a, const float* __restrict__ W1b,
                       const float* __restrict__ W2a, short* __restrict__ Wt,
                       short* __restrict__ Xbf, const int* __restrict__ ei,
                       int* __restrict__ deg, float* __restrict__ smf,
                       const int* __restrict__ batch, int* __restrict__ gb) {
    int idx = blockIdx.x * 256 + threadIdx.x;  // grid 6400*256 = 1,638,400
    if (idx < 1600000) {  // 12.8M floats / 8
        const float4* xr = (const float4*)x + (size_t)idx * 2;
        float4 v0 = xr[0], v1 = xr[1];
        short8 o;
        o[0] = f2bf(v0.x); o[1] = f2bf(v0.y); o[2] = f2bf(v0.z); o[3] = f2bf(v0.w);
        o[4] = f2bf(v1.x); o[5] = f2bf(v1.y); o[6] = f2bf(v1.z); o[7] = f2bf(v1.w);
        *(short8*)(Xbf + (size_t)idx * 8) = o;
    }
    if (idx < EE) atomicAdd(&deg[ei[EE + idx]], 1);
    if (idx < 4112) smf[idx] = 0.0f;
    if (idx < NN) {
        int b = batch[idx];
        int prev = (idx == 0) ? -1 : batch[idx - 1];
        for (int g = prev + 1; g <= b; ++g) gb[g] = idx;
        if (idx == NN - 1)
            for (int g = b + 1; g <= GG; ++g) gb[g] = NN;
    }
    if (idx < 81920) {
        int wi = idx >> 14, r = idx & 16383;
        const float* W = (wi == 0) ? W0a : (wi == 1) ? W0b : (wi == 2) ? W1a
                        : (wi == 3) ? W1b : W2a;
        int k = r >> 7, n = r & 127;
        int ch = n >> 6, ct = (n >> 4) & 3, r16 = n & 15;
        int kc = k >> 3, kk = kc >> 2, q = kc & 3, e = k & 7;
        int lane = r16 + (q << 4);
        Wt[wi * 16384 + ((((ch * 4 + ct) * 4 + kk) * 64 + lane) << 3) + e] =
            f2bf(W[k * 128 + n]);
    }
}

// ---------------- single-kernel scan (scan1+scan3 merged) ----------------
// Block bid computes its global base by DIRECTLY re-reducing deg[0..bid*1024)
// (deg is 400KB, L2-hot; Σ reads ~19.6MB over the grid ≈ 1-2us) — removes
// the bsums dependency and the second scan kernel entirely. Local scan is
// the R12-proven wave-shuffle version (2 barriers, not Hillis-Steele's 30).
__global__ __launch_bounds__(1024) void k_scan(const int* __restrict__ deg,
                                               int* __restrict__ offs,
                                               int* __restrict__ pos) {
    __shared__ int wsum[16];
    __shared__ int sbase[16];
    const int t = threadIdx.x;
    const int bid = blockIdx.x;
    const int i = bid * 1024 + t;
    const int lane = t & 63, wid = t >> 6;

    // ---- base = sum(deg[0 .. bid*1024)) ----
    int tot = 0;
    for (int k = t; k < bid * 1024; k += 1024) tot += deg[k];
#pragma unroll
    for (int off = 1; off < 64; off <<= 1) tot += __shfl_xor(tot, off, 64);
    if (lane == 0) sbase[wid] = tot;

    // ---- local inclusive scan (wave shuffle) ----
    int v = (i < NN) ? deg[i] : 0;
    int xval = v;
#pragma unroll
    for (int off = 1; off < 64; off <<= 1) {
        int y = __shfl_up(xval, off, 64);
        if (lane >= off) xval += y;
    }
    if (lane == 63) wsum[wid] = xval;
    __syncthreads();
    if (wid == 0) {
        int b = (lane < 16) ? sbase[lane] : 0;
#pragma unroll
        for (int off = 1; off < 16; off <<= 1) b += __shfl_xor(b, off, 16);
        int w = (lane < 16) ? wsum[lane] : 0;
#pragma unroll
        for (int off = 1; off < 16; off <<= 1) {
            int y = __shfl_up(w, off, 16);
            if ((lane & 15) >= off) w += y;
        }
        if (lane < 16) { wsum[lane] = w; sbase[lane] = b; }
    }
    __syncthreads();
    const int base = sbase[0];
    const int wbase = (wid > 0) ? wsum[wid - 1] : 0;
    if (i < NN) {
        int o = base + wbase + xval - v;
        offs[i] = o;
        pos[i] = o;
    }
    if (i == 0) offs[NN] = EE;
}

__global__ void k_fill(const int* __restrict__ ei, int* __restrict__ pos,
                       int* __restrict__ csr) {
    int e = blockIdx.x * 256 + threadIdx.x;
    if (e < EE) {
        int d = ei[EE + e];
        int p = atomicAdd(&pos[d], 1);
        csr[p] = ei[e];
    }
}

// ---------------- fused gather + GIN MLP, bf16 MFMA, 128x128 tile ----------------
// R8-proven body (measured floor: ~57.5us/dispatch): 512 threads (8 waves),
// BM=128, LDS ~37KB, __launch_bounds__(512,4) -> ~60 arch VGPR, no spill.
// REGISTER LAW (R1/R4/R7, 3x confirmed): needs ~92 unified regs; any cap
// below spills catastrophically. R10: occupancy is NOT the binding constraint.
// R12 arithmetic: 16 rows in flight/wave x 16 waves/CU / ~850cy round
// ~= 2.4 TB/s — matches measured: the gather is fabric/L3-random-read bound.
// This structure is at its floor.
// Weights read as MFMA B-fragments straight from global (fragment-ordered,
// L2-resident, 1KB coalesced per wave-load, shared by all blocks).
// wave w: rh = w&3 (rows rh*32..+32), ch = w>>2 (cols ch*64..+64); acc[2][4].
// MODE 0: input Xbf (no BN), full MLP -> hout + BN stats (8-replica)
// MODE 1: input bf16 h, BN+ReLU on gathered rows, full MLP -> hout + stats
// MODE 2: input bf16 h, BN+ReLU, gemm1 -> fused dot w2 -> z + (s,ss) replicas
template <int MODE>
__global__ __launch_bounds__(512, 4) void k_gmlp(const short* __restrict__ hin,
                                                 const int* __restrict__ offs,
                                                 const int* __restrict__ csr,
                                                 const float* __restrict__ rep,
                                                 const float* __restrict__ g,
                                                 const float* __restrict__ be,
                                                 const short* __restrict__ Wta,
                                                 const float* __restrict__ ba,
                                                 const short* __restrict__ Wtb,
                                                 const float* __restrict__ bb,
                                                 short* __restrict__ hout,
                                                 float* __restrict__ statsRep,
                                                 const float* __restrict__ w2,
                                                 const float* __restrict__ b2,
                                                 float* __restrict__ z,
                                                 float* __restrict__ s2rep) {
    __shared__ short Asb[16384];   // 128x128 bf16, swizzled
    __shared__ float parS[128], parH[128];
    __shared__ float redS[1024];
    const int t = threadIdx.x;
    const int row0 = blockIdx.x * 128;
    const int lane = t & 63, wave = t >> 6;
    const int r16 = lane & 15, q = lane >> 4;
    const int rh = wave & 3, ch = wave >> 2;
    const int RA = rh * 32, CB = ch * 64;
    const int l = t & 15;

    // ---- BN params (MODE != 0) ----
    if constexpr (MODE != 0) {
        if (t < 128) {
            float s = 0.f, ss = 0.f;
#pragma unroll
            for (int r = 0; r < 8; ++r) {
                s += rep[r * 256 + t];
                ss += rep[r * 256 + 128 + t];
            }
            const float inv = 1.0f / (float)NN;
            float mu = s * inv;
            float var = ss * inv - mu * mu;
            float sc = g[t] / sqrtf(var + BN_EPS);
            parS[t] = sc;
            parH[t] = be[t] - mu * sc;
        }
        __syncthreads();
    }

    // per-wave fragment base pointers (global, fragment-ordered weights)
    const short* wA = Wta + (size_t)((ch * 1024 + lane) << 3);
    const short* wB = (MODE != 2) ? (Wtb + (size_t)((ch * 1024 + lane) << 3)) : nullptr;

    // ---- fused gather: 4 nodes/thread, 16 lanes/node, 4-wide pipelined ----
    float sc8[8], sh8[8];
    if constexpr (MODE != 0) {
#pragma unroll
        for (int u = 0; u < 8; ++u) { sc8[u] = parS[l * 8 + u]; sh8[u] = parH[l * 8 + u]; }
    }
#pragma unroll
    for (int p = 0; p < 4; ++p) {
        int r = p * 32 + (t >> 4);
        int gr = row0 + r;
        float f8[8] = {0.f, 0.f, 0.f, 0.f, 0.f, 0.f, 0.f, 0.f};
        if (gr < NN) {
            int j0 = offs[gr], j1 = offs[gr + 1];
            short8 v = *(const short8*)(hin + (size_t)gr * 128 + l * 8);
#pragma unroll
            for (int k = 0; k < 8; ++k)
                f8[k] = (MODE != 0) ? fmaxf(fmaf(bf2f(v[k]), sc8[k], sh8[k]), 0.f) : bf2f(v[k]);
            int jlast = j1 - 1;
            int jj = j0;
            int s0 = 0, s1 = 0, s2 = 0, s3 = 0;
            if (jj < j1) {
                s0 = csr[jj];
                s1 = csr[min(jj + 1, jlast)];
                s2 = csr[min(jj + 2, jlast)];
                s3 = csr[min(jj + 3, jlast)];
            }
            while (jj < j1) {
                float m1 = (jj + 1 <= jlast) ? 1.f : 0.f;
                float m2 = (jj + 2 <= jlast) ? 1.f : 0.f;
                float m3 = (jj + 3 <= jlast) ? 1.f : 0.f;
                // row loads for the current batch (use old s0..s3)
                short8 w0 = *(const short8*)(hin + (size_t)s0 * 128 + l * 8);
                short8 w1 = *(const short8*)(hin + (size_t)s1 * 128 + l * 8);
                short8 w2v = *(const short8*)(hin + (size_t)s2 * 128 + l * 8);
                short8 w3 = *(const short8*)(hin + (size_t)s3 * 128 + l * 8);
                // prefetch next batch's indices — independent of w0..w3
                int jn = jj + 4;
                if (jn < j1) {
                    s0 = csr[jn];
                    s1 = csr[min(jn + 1, jlast)];
                    s2 = csr[min(jn + 2, jlast)];
                    s3 = csr[min(jn + 3, jlast)];
                }
#pragma unroll
                for (int k = 0; k < 8; ++k) {
                    if constexpr (MODE != 0) {
                        f8[k] += fmaxf(fmaf(bf2f(w0[k]), sc8[k], sh8[k]), 0.f);
                        f8[k] = fmaf(m1, fmaxf(fmaf(bf2f(w1[k]), sc8[k], sh8[k]), 0.f), f8[k]);
                        f8[k] = fmaf(m2, fmaxf(fmaf(bf2f(w2v[k]), sc8[k], sh8[k]), 0.f), f8[k]);
                        f8[k] = fmaf(m3, fmaxf(fmaf(bf2f(w3[k]), sc8[k], sh8[k]), 0.f), f8[k]);
                    } else {
                        f8[k] += bf2f(w0[k]);
                        f8[k] = fmaf(m1, bf2f(w1[k]), f8[k]);
                        f8[k] = fmaf(m2, bf2f(w2v[k]), f8[k]);
                        f8[k] = fmaf(m3, bf2f(w3[k]), f8[k]);
                    }
                }
                jj = jn;
            }
        }
        short8 o;
#pragma unroll
        for (int k = 0; k < 8; ++k) o[k] = f2bf(f8[k]);
        *(short8*)&Asb[swz(r, l)] = o;
    }
    __syncthreads();

    // ---- gemm1 (A from LDS, B-fragments from global/L2) ----
    f32x4 acc[2][4];
#pragma unroll
    for (int rt = 0; rt < 2; ++rt)
#pragma unroll
        for (int ct = 0; ct < 4; ++ct) acc[rt][ct] = (f32x4)0.f;
#pragma unroll
    for (int kk = 0; kk < 4; ++kk) {
        short8 b[4], a[2];
#pragma unroll
        for (int ct = 0; ct < 4; ++ct)
            b[ct] = *(const short8*)(wA + ((ct * 4 + kk) << 9));
#pragma unroll
        for (int rt = 0; rt < 2; ++rt)
            a[rt] = *(const short8*)&Asb[swz(RA + rt * 16 + r16, kk * 4 + q)];
#pragma unroll
        for (int rt = 0; rt < 2; ++rt)
#pragma unroll
            for (int ct = 0; ct < 4; ++ct)
                acc[rt][ct] = __builtin_amdgcn_mfma_f32_16x16x32_bf16(a[rt], b[ct], acc[rt][ct], 0, 0, 0);
    }
    __syncthreads();  // gemm1 LDS reads done

    // mid = relu(acc + ba) -> Asb
    float bav[4];
#pragma unroll
    for (int ct = 0; ct < 4; ++ct) bav[ct] = ba[CB + ct * 16 + r16];
#pragma unroll
    for (int rt = 0; rt < 2; ++rt)
#pragma unroll
        for (int ct = 0; ct < 4; ++ct)
#pragma unroll
            for (int rg = 0; rg < 4; ++rg) {
                float m = fmaxf(acc[rt][ct][rg] + bav[ct], 0.f);
                Asb[swze(RA + rt * 16 + q * 4 + rg, CB + ct * 16 + r16)] = f2bf(m);
            }
    __syncthreads();

    if constexpr (MODE == 2) {
        // fused final linear: z = mid . w2 + b2, plus (s,ss)
        const int rr = t >> 4;
        float4 w0 = ((const float4*)w2)[l * 2];
        float4 w1 = ((const float4*)w2)[l * 2 + 1];
        float b2v = b2[0];
        float s = 0.f, ss = 0.f;
#pragma unroll
        for (int p = 0; p < 4; ++p) {
            int r = p * 32 + rr;
            int gr = row0 + r;
            short8 v = *(const short8*)&Asb[swz(r, l)];
            float pp = bf2f(v[0]) * w0.x + bf2f(v[1]) * w0.y + bf2f(v[2]) * w0.z +
                       bf2f(v[3]) * w0.w + bf2f(v[4]) * w1.x + bf2f(v[5]) * w1.y +
                       bf2f(v[6]) * w1.z + bf2f(v[7]) * w1.w;
#pragma unroll
            for (int off = 1; off < 16; off <<= 1) pp += __shfl_xor(pp, off, 16);
            if (l == 0 && gr < NN) {
                float h2 = pp + b2v;
                z[gr] = h2;
                s += h2;
                ss += h2 * h2;
            }
        }
        s += __shfl_xor(s, 16); s += __shfl_xor(s, 32);
        ss += __shfl_xor(ss, 16); ss += __shfl_xor(ss, 32);
        if ((t & 63) == 0) { redS[wave * 2] = s; redS[wave * 2 + 1] = ss; }
        __syncthreads();
        if (t == 0) {
            float S = 0.f, SS = 0.f;
#pragma unroll
            for (int w = 0; w < 8; ++w) { S += redS[w * 2]; SS += redS[w * 2 + 1]; }
            int rp = (blockIdx.x & 7) * 2;
            unsafeAtomicAdd(&s2rep[rp], S);
            unsafeAtomicAdd(&s2rep[rp + 1], SS);
        }
        return;
    } else {
        // ---- gemm2 ----
#pragma unroll
        for (int rt = 0; rt < 2; ++rt)
#pragma unroll
            for (int ct = 0; ct < 4; ++ct) acc[rt][ct] = (f32x4)0.f;
#pragma unroll
        for (int kk = 0; kk < 4; ++kk) {
            short8 b[4], a[2];
#pragma unroll
            for (int ct = 0; ct < 4; ++ct)
                b[ct] = *(const short8*)(wB + ((ct * 4 + kk) << 9));
#pragma unroll
            for (int rt = 0; rt < 2; ++rt)
                a[rt] = *(const short8*)&Asb[swz(RA + rt * 16 + r16, kk * 4 + q)];
#pragma unroll
            for (int rt = 0; rt < 2; ++rt)
#pragma unroll
                for (int ct = 0; ct < 4; ++ct)
                    acc[rt][ct] = __builtin_amdgcn_mfma_f32_16x16x32_bf16(a[rt], b[ct], acc[rt][ct], 0, 0, 0);
        }
        __syncthreads();  // gemm2 LDS reads done

        float bbv[4];
#pragma unroll
        for (int ct = 0; ct < 4; ++ct) bbv[ct] = bb[CB + ct * 16 + r16];
        float s[4] = {0.f, 0.f, 0.f, 0.f}, ss[4] = {0.f, 0.f, 0.f, 0.f};
#pragma unroll
        for (int rt = 0; rt < 2; ++rt)
#pragma unroll
            for (int ct = 0; ct < 4; ++ct)
#pragma unroll
                for (int rg = 0; rg < 4; ++rg) {
                    int lr = RA + rt * 16 + q * 4 + rg;
                    int gr = row0 + lr;
                    float hv = acc[rt][ct][rg] + bbv[ct];
                    if (gr < NN) { s[ct] += hv; ss[ct] += hv * hv; }
                    Asb[swze(lr, CB + ct * 16 + r16)] = f2bf(hv);
                }
#pragma unroll
        for (int ct = 0; ct < 4; ++ct) {
            s[ct] += __shfl_xor(s[ct], 16);
            s[ct] += __shfl_xor(s[ct], 32);
            ss[ct] += __shfl_xor(ss[ct], 16);
            ss[ct] += __shfl_xor(ss[ct], 32);
        }
        if (lane < 16) {
#pragma unroll
            for (int ct = 0; ct < 4; ++ct) {
                int col = CB + ct * 16 + r16;
                redS[rh * 256 + col] = s[ct];
                redS[rh * 256 + 128 + col] = ss[ct];
            }
        }
        __syncthreads();
        if (t < 256) {
            float v = redS[t] + redS[256 + t] + redS[512 + t] + redS[768 + t];
            unsafeAtomicAdd(&statsRep[(blockIdx.x & 7) * 256 + t], v);
        }
        // coalesced bf16 store of h tile
#pragma unroll
        for (int i = 0; i < 4; ++i) {
            int f = i * 512 + t;
            int r = f >> 4, c8 = f & 15;
            int gr = row0 + r;
            if (gr < NN)
                *(short8*)(hout + (size_t)gr * 128 + c8 * 8) = *(const short8*)&Asb[swz(r, c8)];
        }
    }
}

// fused BN(1) + segment softmax(temp 5): one block per graph; graph bounds
// precomputed in k_prep (gb) — no per-block binary search.
__global__ void k_softmax(const float* __restrict__ zr, const float* __restrict__ s2rep,
                          const float* __restrict__ g2, const float* __restrict__ be2,
                          const int* __restrict__ gb, float* __restrict__ out) {
    __shared__ float rb[4];
    const int g = blockIdx.x, t = threadIdx.x;
    const int lo = gb[g], hi = gb[g + 1];
    float s = 0.f, ssq = 0.f;
#pragma unroll
    for (int i = 0; i < 8; ++i) { s += s2rep[i * 2]; ssq += s2rep[i * 2 + 1]; }
    const float mu = s / (float)NN;
    const float var = ssq / (float)NN - mu * mu;
    const float sc = g2[0] / sqrtf(var + BN_EPS) * 0.2f;
    const float sh = (be2[0] - mu * g2[0] / sqrtf(var + BN_EPS)) * 0.2f;

    float m = -INFINITY;
    for (int i = lo + t; i < hi; i += 256) m = fmaxf(m, fmaf(zr[i], sc, sh));
#pragma unroll
    for (int off = 1; off < 64; off <<= 1) m = fmaxf(m, __shfl_xor(m, off, 64));
    if ((t & 63) == 0) rb[t >> 6] = m;
    __syncthreads();
    float gmax = fmaxf(fmaxf(rb[0], rb[1]), fmaxf(rb[2], rb[3]));
    __syncthreads();

    float sum = 0.f;
    for (int i = lo + t; i < hi; i += 256) {
        float e = expf(fmaf(zr[i], sc, sh) - gmax);
        out[i] = e;
        sum += e;
    }
#pragma unroll
    for (int off = 1; off < 64; off <<= 1) sum += __shfl_xor(sum, off, 64);
    if ((t & 63) == 0) rb[t >> 6] = sum;
    __syncthreads();
    float S = rb[0] + rb[1] + rb[2] + rb[3];
    float inv = 1.0f / (S + 1e-16f);
    for (int i = lo + t; i < hi; i += 256) out[i] *= inv;
}

extern "C" void kernel_launch(void* const* d_in, const int* in_sizes, int n_in,
                              void* d_out, int out_size, void* d_ws, size_t ws_size,
                              hipStream_t stream) {
    const float* x   = (const float*)d_in[0];
    const int* ei    = (const int*)d_in[1];
    const int* batch = (const int*)d_in[2];
    const float *W0a = (const float*)d_in[3],  *b0a = (const float*)d_in[4];
    const float *W0b = (const float*)d_in[5],  *b0b = (const float*)d_in[6];
    const float *g0  = (const float*)d_in[7],  *be0 = (const float*)d_in[8];
    const float *W1a = (const float*)d_in[9],  *b1a = (const float*)d_in[10];
    const float *W1b = (const float*)d_in[11], *b1b = (const float*)d_in[12];
    const float *g1  = (const float*)d_in[13], *be1 = (const float*)d_in[14];
    const float *W2a = (const float*)d_in[15], *b2a = (const float*)d_in[16];
    const float *W2b = (const float*)d_in[17], *b2b = (const float*)d_in[18];
    const float *g2  = (const float*)d_in[19], *be2 = (const float*)d_in[20];
    float* out = (float*)d_out;

    char* wsb = (char*)d_ws;
    short* Abf = (short*)wsb;
    short* Bbf = (short*)(wsb + 25600000);
    float* Zb  = (float*)(wsb + 51200000);
    float* SMf = (float*)(wsb + 51600000);
    float* S0r = SMf;               // 8 x 256
    float* S1r = SMf + 2048;        // 8 x 256
    float* S2r = SMf + 4096;        // 8 x 2
    int* gb    = (int*)(wsb + 51616448);  // 129 graph boundaries
    int* offs  = (int*)(wsb + 51620000);
    int* csr   = (int*)(wsb + 52020516);
    short* Wt  = (short*)(wsb + 54580544);
    short* Xbf = (short*)(wsb + 54744384);
    // deg/pos alias Abf during CSR build
    int* deg = (int*)wsb;
    int* pos = (int*)(wsb + 400000);

    const int gE    = (EE + 255) / 256;     // 2500
    const int gGmlp = (NN + 127) / 128;     // 782

    // zero deg (stats are zeroed inside k_prep)
    (void)hipMemsetAsync(deg, 0, NN * sizeof(int), stream);

    // fused prep: x->bf16, weights->fragment order, histogram, stats zero, gb
    k_prep<<<6400, 256, 0, stream>>>(x, W0a, W0b, W1a, W1b, W2a, Wt, Xbf, ei,
                                     deg, SMf, batch, gb);

    // ---- CSR build: single scan kernel + fill ----
    k_scan<<<NBLK, 1024, 0, stream>>>(deg, offs, pos);
    k_fill<<<gE, 256, 0, stream>>>(ei, pos, csr);

    // layer 0: fused gather(Xbf) + MLP -> Abf + stats
    k_gmlp<0><<<gGmlp, 512, 0, stream>>>(Xbf, offs, csr, nullptr, nullptr, nullptr,
                                         Wt, b0a, Wt + 16384, b0b, Abf, S0r,
                                         nullptr, nullptr, nullptr, nullptr);
    // layer 1: fused gather(Abf, BN0+ReLU) + MLP -> Bbf + stats
    k_gmlp<1><<<gGmlp, 512, 0, stream>>>(Abf, offs, csr, S0r, g0, be0,
                                         Wt + 2 * 16384, b1a, Wt + 3 * 16384, b1b, Bbf, S1r,
                                         nullptr, nullptr, nullptr, nullptr);
    // layer 2: fused gather(Bbf, BN1+ReLU) + gemm1 + final dot -> Zb + s2
    k_gmlp<2><<<gGmlp, 512, 0, stream>>>(Bbf, offs, csr, S1r, g1, be1,
                                         Wt + 4 * 16384, b2a, nullptr, nullptr,
                                         nullptr, nullptr, W2b, b2b, Zb, S2r);

    // fused BN(1) + segment softmax (temperature 5)
    k_softmax<<<GG, 256, 0, stream>>>(Zb, S2r, g2, be2, gb, out);
}

// Round 14
// 347.531 us; speedup vs baseline: 1.0263x; 1.0263x over previous
//
#include <hip/hip_runtime.h>
#include <math.h>

#define NN 100000
#define EE 640000
#define GG 128
#define BN_EPS 1e-5f
#define NBLK 98  // ceil(NN/1024)

typedef __attribute__((ext_vector_type(8))) short short8;
typedef __attribute__((ext_vector_type(4))) float f32x4;

// ---------------- ws layout (byte offsets) ----------------
// Abf : [0,          25,600,000)   N x 128 bf16 (h0)
// Bbf : [25,600,000, 51,200,000)   N x 128 bf16 (h1)
// Z   : [51,200,000, 51,600,000)   N fp32
// SM  : [51,600,000, +16,448)      S0r(8x256) S1r(8x256) S2r(16)
// gb  : [51,616,448, +516)         129 int graph boundaries (start[g])
// offs: [51,620,000, +400,004)     N+1 int
// bsum: [52,020,004, +512)
// csr : [52,020,516, +2,560,000)
// Wt  : [54,580,544, +163,840)     5 x 128x128 bf16 (MFMA-fragment-ordered)
// Xbf : [54,744,384, +25,600,000)  N x 128 bf16 (x pre-rounded)
// deg/pos alias Abf region during CSR build (Abf not yet live).

__device__ __forceinline__ short f2bf(float f) {
    unsigned u = __float_as_uint(f);
    u += 0x7fffu + ((u >> 16) & 1);
    return (short)(u >> 16);
}
__device__ __forceinline__ float bf2f(short s) {
    return __uint_as_float(((unsigned)(unsigned short)s) << 16);
}
// XOR-swizzled LDS addressing (16B chunks), padding-free & ~conflict-free
__device__ __forceinline__ int swz(int row, int chunk) {
    return row * 128 + ((chunk ^ (row & 15)) << 3);
}
__device__ __forceinline__ int swze(int row, int col) {
    return row * 128 + (((col >> 3) ^ (row & 15)) << 3) + (col & 7);
}

// ---------------- fused prep ----------------
// x->bf16 + weights->fragment order + degree histogram + zero stats +
// graph-boundary table gb[g] = first node index of graph g (batch sorted;
// every g in [0,128] written exactly once). R11 lesson: launch boundaries
// are cheap under graph replay; the small kernels' EXECUTION is the cost —
// so fold cheap independent work here, never global-sync.
// R13 lesson: merging scan1+scan3 via per-block re-reduction regresses
// (tail blocks re-read 400KB with 1 block's threads) — keep the 2-kernel scan.
// Fragment order: value W[k][n] lands at
//   wi*16384 + (((ch*4+ct)*4+kk)*64 + lane)*8 + e
// ch=n>>6, ct=(n>>4)&3, r16=n&15, kc=k>>3, kk=kc>>2, q=kc&3,
// lane=r16+16*q, e=k&7  => a wave's B-fragment load is one contiguous 1KB.
__global__ void k_prep(const float* __restrict__ x,
                       const float* __restrict__ W0a, const float* __restrict__ W0b,
                       const float* __restrict__ W1a, const float* __restrict__ W1b,
                       const float* __restrict__ W2a, short* __restrict__ Wt,
                       short* __restrict__ Xbf, const int* __restrict__ ei,
                       int* __restrict__ deg, float* __restrict__ smf,
                       const int* __restrict__ batch, int* __restrict__ gb) {
    int idx = blockIdx.x * 256 + threadIdx.x;  // grid 6400*256 = 1,638,400
    if (idx < 1600000) {  // 12.8M floats / 8
        const float4* xr = (const float4*)x + (size_t)idx * 2;
        float4 v0 = xr[0], v1 = xr[1];
        short8 o;
        o[0] = f2bf(v0.x); o[1] = f2bf(v0.y); o[2] = f2bf(v0.z); o[3] = f2bf(v0.w);
        o[4] = f2bf(v1.x); o[5] = f2bf(v1.y); o[6] = f2bf(v1.z); o[7] = f2bf(v1.w);
        *(short8*)(Xbf + (size_t)idx * 8) = o;
    }
    if (idx < EE) atomicAdd(&deg[ei[EE + idx]], 1);
    if (idx < 4112) smf[idx] = 0.0f;
    if (idx < NN) {
        int b = batch[idx];
        int prev = (idx == 0) ? -1 : batch[idx - 1];
        for (int g = prev + 1; g <= b; ++g) gb[g] = idx;
        if (idx == NN - 1)
            for (int g = b + 1; g <= GG; ++g) gb[g] = NN;
    }
    if (idx < 81920) {
        int wi = idx >> 14, r = idx & 16383;
        const float* W = (wi == 0) ? W0a : (wi == 1) ? W0b : (wi == 2) ? W1a
                        : (wi == 3) ? W1b : W2a;
        int k = r >> 7, n = r & 127;
        int ch = n >> 6, ct = (n >> 4) & 3, r16 = n & 15;
        int kc = k >> 3, kk = kc >> 2, q = kc & 3, e = k & 7;
        int lane = r16 + (q << 4);
        Wt[wi * 16384 + ((((ch * 4 + ct) * 4 + kk) * 64 + lane) << 3) + e] =
            f2bf(W[k * 128 + n]);
    }
}

// wave-shuffle scan: 2 syncthreads instead of Hillis-Steele's 30
__global__ __launch_bounds__(1024) void k_scan1(const int* __restrict__ deg,
                                                int* __restrict__ offs,
                                                int* __restrict__ bsums) {
    __shared__ int wsum[16];
    const int t = threadIdx.x;
    const int i = blockIdx.x * 1024 + t;
    const int lane = t & 63, wid = t >> 6;
    int v = (i < NN) ? deg[i] : 0;
    int xval = v;
#pragma unroll
    for (int off = 1; off < 64; off <<= 1) {
        int y = __shfl_up(xval, off, 64);
        if (lane >= off) xval += y;
    }
    if (lane == 63) wsum[wid] = xval;
    __syncthreads();
    if (wid == 0) {
        int w = (lane < 16) ? wsum[lane] : 0;
#pragma unroll
        for (int off = 1; off < 16; off <<= 1) {
            int y = __shfl_up(w, off, 16);
            if ((lane & 15) >= off) w += y;
        }
        if (lane < 16) wsum[lane] = w;
    }
    __syncthreads();
    int base = (wid > 0) ? wsum[wid - 1] : 0;
    int inc = xval + base;  // block-local inclusive
    if (i < NN) offs[i] = inc - v;
    if (t == 1023) bsums[blockIdx.x] = inc;
}

// scan3 with scan2 folded in: each block reduces bsums prefix itself
__global__ __launch_bounds__(1024) void k_scan3(int* __restrict__ offs,
                                                const int* __restrict__ bsums,
                                                int* __restrict__ pos) {
    __shared__ int smb[128];
    __shared__ int baseS;
    int t = threadIdx.x;
    if (t < 128) smb[t] = (t < NBLK) ? bsums[t] : 0;
    __syncthreads();
    if (t == 0) {
        int b = 0;
        for (int i = 0; i < (int)blockIdx.x; ++i) b += smb[i];
        baseS = b;
    }
    __syncthreads();
    int i = blockIdx.x * 1024 + t;
    if (i < NN) {
        int o = offs[i] + baseS;
        offs[i] = o;
        pos[i] = o;
    }
    if (i == 0) offs[NN] = EE;
}

__global__ void k_fill(const int* __restrict__ ei, int* __restrict__ pos,
                       int* __restrict__ csr) {
    int e = blockIdx.x * 256 + threadIdx.x;
    if (e < EE) {
        int d = ei[EE + e];
        int p = atomicAdd(&pos[d], 1);
        csr[p] = ei[e];
    }
}

// ---------------- fused gather + GIN MLP, bf16 MFMA, 128x128 tile ----------------
// R8/R12-proven body (measured floor: ~57.5us/dispatch): 512 threads (8 waves),
// BM=128, LDS ~37KB, __launch_bounds__(512,4) -> ~60 arch VGPR, no spill.
// REGISTER LAW (R1/R4/R7, 3x confirmed): needs ~92 unified regs; any cap
// below spills catastrophically. R10: occupancy is NOT the binding constraint.
// R12 arithmetic: 16 rows in flight/wave x 16 waves/CU / ~850cy round
// ~= 2.4 TB/s — matches measured: the gather is fabric/L3-random-read bound.
// This structure is at its floor.
// Weights read as MFMA B-fragments straight from global (fragment-ordered,
// L2-resident, 1KB coalesced per wave-load, shared by all blocks).
// wave w: rh = w&3 (rows rh*32..+32), ch = w>>2 (cols ch*64..+64); acc[2][4].
// MODE 0: input Xbf (no BN), full MLP -> hout + BN stats (8-replica)
// MODE 1: input bf16 h, BN+ReLU on gathered rows, full MLP -> hout + stats
// MODE 2: input bf16 h, BN+ReLU, gemm1 -> fused dot w2 -> z + (s,ss) replicas
template <int MODE>
__global__ __launch_bounds__(512, 4) void k_gmlp(const short* __restrict__ hin,
                                                 const int* __restrict__ offs,
                                                 const int* __restrict__ csr,
                                                 const float* __restrict__ rep,
                                                 const float* __restrict__ g,
                                                 const float* __restrict__ be,
                                                 const short* __restrict__ Wta,
                                                 const float* __restrict__ ba,
                                                 const short* __restrict__ Wtb,
                                                 const float* __restrict__ bb,
                                                 short* __restrict__ hout,
                                                 float* __restrict__ statsRep,
                                                 const float* __restrict__ w2,
                                                 const float* __restrict__ b2,
                                                 float* __restrict__ z,
                                                 float* __restrict__ s2rep) {
    __shared__ short Asb[16384];   // 128x128 bf16, swizzled
    __shared__ float parS[128], parH[128];
    __shared__ float redS[1024];
    const int t = threadIdx.x;
    const int row0 = blockIdx.x * 128;
    const int lane = t & 63, wave = t >> 6;
    const int r16 = lane & 15, q = lane >> 4;
    const int rh = wave & 3, ch = wave >> 2;
    const int RA = rh * 32, CB = ch * 64;
    const int l = t & 15;

    // ---- BN params (MODE != 0) ----
    if constexpr (MODE != 0) {
        if (t < 128) {
            float s = 0.f, ss = 0.f;
#pragma unroll
            for (int r = 0; r < 8; ++r) {
                s += rep[r * 256 + t];
                ss += rep[r * 256 + 128 + t];
            }
            const float inv = 1.0f / (float)NN;
            float mu = s * inv;
            float var = ss * inv - mu * mu;
            float sc = g[t] / sqrtf(var + BN_EPS);
            parS[t] = sc;
            parH[t] = be[t] - mu * sc;
        }
        __syncthreads();
    }

    // per-wave fragment base pointers (global, fragment-ordered weights)
    const short* wA = Wta + (size_t)((ch * 1024 + lane) << 3);
    const short* wB = (MODE != 2) ? (Wtb + (size_t)((ch * 1024 + lane) << 3)) : nullptr;

    // ---- fused gather: 4 nodes/thread, 16 lanes/node, 4-wide pipelined ----
    float sc8[8], sh8[8];
    if constexpr (MODE != 0) {
#pragma unroll
        for (int u = 0; u < 8; ++u) { sc8[u] = parS[l * 8 + u]; sh8[u] = parH[l * 8 + u]; }
    }
#pragma unroll
    for (int p = 0; p < 4; ++p) {
        int r = p * 32 + (t >> 4);
        int gr = row0 + r;
        float f8[8] = {0.f, 0.f, 0.f, 0.f, 0.f, 0.f, 0.f, 0.f};
        if (gr < NN) {
            int j0 = offs[gr], j1 = offs[gr + 1];
            short8 v = *(const short8*)(hin + (size_t)gr * 128 + l * 8);
#pragma unroll
            for (int k = 0; k < 8; ++k)
                f8[k] = (MODE != 0) ? fmaxf(fmaf(bf2f(v[k]), sc8[k], sh8[k]), 0.f) : bf2f(v[k]);
            int jlast = j1 - 1;
            int jj = j0;
            int s0 = 0, s1 = 0, s2 = 0, s3 = 0;
            if (jj < j1) {
                s0 = csr[jj];
                s1 = csr[min(jj + 1, jlast)];
                s2 = csr[min(jj + 2, jlast)];
                s3 = csr[min(jj + 3, jlast)];
            }
            while (jj < j1) {
                float m1 = (jj + 1 <= jlast) ? 1.f : 0.f;
                float m2 = (jj + 2 <= jlast) ? 1.f : 0.f;
                float m3 = (jj + 3 <= jlast) ? 1.f : 0.f;
                // row loads for the current batch (use old s0..s3)
                short8 w0 = *(const short8*)(hin + (size_t)s0 * 128 + l * 8);
                short8 w1 = *(const short8*)(hin + (size_t)s1 * 128 + l * 8);
                short8 w2v = *(const short8*)(hin + (size_t)s2 * 128 + l * 8);
                short8 w3 = *(const short8*)(hin + (size_t)s3 * 128 + l * 8);
                // prefetch next batch's indices — independent of w0..w3
                int jn = jj + 4;
                if (jn < j1) {
                    s0 = csr[jn];
                    s1 = csr[min(jn + 1, jlast)];
                    s2 = csr[min(jn + 2, jlast)];
                    s3 = csr[min(jn + 3, jlast)];
                }
#pragma unroll
                for (int k = 0; k < 8; ++k) {
                    if constexpr (MODE != 0) {
                        f8[k] += fmaxf(fmaf(bf2f(w0[k]), sc8[k], sh8[k]), 0.f);
                        f8[k] = fmaf(m1, fmaxf(fmaf(bf2f(w1[k]), sc8[k], sh8[k]), 0.f), f8[k]);
                        f8[k] = fmaf(m2, fmaxf(fmaf(bf2f(w2v[k]), sc8[k], sh8[k]), 0.f), f8[k]);
                        f8[k] = fmaf(m3, fmaxf(fmaf(bf2f(w3[k]), sc8[k], sh8[k]), 0.f), f8[k]);
                    } else {
                        f8[k] += bf2f(w0[k]);
                        f8[k] = fmaf(m1, bf2f(w1[k]), f8[k]);
                        f8[k] = fmaf(m2, bf2f(w2v[k]), f8[k]);
                        f8[k] = fmaf(m3, bf2f(w3[k]), f8[k]);
                    }
                }
                jj = jn;
            }
        }
        short8 o;
#pragma unroll
        for (int k = 0; k < 8; ++k) o[k] = f2bf(f8[k]);
        *(short8*)&Asb[swz(r, l)] = o;
    }
    __syncthreads();

    // ---- gemm1 (A from LDS, B-fragments from global/L2) ----
    f32x4 acc[2][4];
#pragma unroll
    for (int rt = 0; rt < 2; ++rt)
#pragma unroll
        for (int ct = 0; ct < 4; ++ct) acc[rt][ct] = (f32x4)0.f;
#pragma unroll
    for (int kk = 0; kk < 4; ++kk) {
        short8 b[4], a[2];
#pragma unroll
        for (int ct = 0; ct < 4; ++ct)
            b[ct] = *(const short8*)(wA + ((ct * 4 + kk) << 9));
#pragma unroll
        for (int rt = 0; rt < 2; ++rt)
            a[rt] = *(const short8*)&Asb[swz(RA + rt * 16 + r16, kk * 4 + q)];
#pragma unroll
        for (int rt = 0; rt < 2; ++rt)
#pragma unroll
            for (int ct = 0; ct < 4; ++ct)
                acc[rt][ct] = __builtin_amdgcn_mfma_f32_16x16x32_bf16(a[rt], b[ct], acc[rt][ct], 0, 0, 0);
    }
    __syncthreads();  // gemm1 LDS reads done

    // mid = relu(acc + ba) -> Asb
    float bav[4];
#pragma unroll
    for (int ct = 0; ct < 4; ++ct) bav[ct] = ba[CB + ct * 16 + r16];
#pragma unroll
    for (int rt = 0; rt < 2; ++rt)
#pragma unroll
        for (int ct = 0; ct < 4; ++ct)
#pragma unroll
            for (int rg = 0; rg < 4; ++rg) {
                float m = fmaxf(acc[rt][ct][rg] + bav[ct], 0.f);
                Asb[swze(RA + rt * 16 + q * 4 + rg, CB + ct * 16 + r16)] = f2bf(m);
            }
    __syncthreads();

    if constexpr (MODE == 2) {
        // fused final linear: z = mid . w2 + b2, plus (s,ss)
        const int rr = t >> 4;
        float4 w0 = ((const float4*)w2)[l * 2];
        float4 w1 = ((const float4*)w2)[l * 2 + 1];
        float b2v = b2[0];
        float s = 0.f, ss = 0.f;
#pragma unroll
        for (int p = 0; p < 4; ++p) {
            int r = p * 32 + rr;
            int gr = row0 + r;
            short8 v = *(const short8*)&Asb[swz(r, l)];
            float pp = bf2f(v[0]) * w0.x + bf2f(v[1]) * w0.y + bf2f(v[2]) * w0.z +
                       bf2f(v[3]) * w0.w + bf2f(v[4]) * w1.x + bf2f(v[5]) * w1.y +
                       bf2f(v[6]) * w1.z + bf2f(v[7]) * w1.w;
#pragma unroll
            for (int off = 1; off < 16; off <<= 1) pp += __shfl_xor(pp, off, 16);
            if (l == 0 && gr < NN) {
                float h2 = pp + b2v;
                z[gr] = h2;
                s += h2;
                ss += h2 * h2;
            }
        }
        s += __shfl_xor(s, 16); s += __shfl_xor(s, 32);
        ss += __shfl_xor(ss, 16); ss += __shfl_xor(ss, 32);
        if ((t & 63) == 0) { redS[wave * 2] = s; redS[wave * 2 + 1] = ss; }
        __syncthreads();
        if (t == 0) {
            float S = 0.f, SS = 0.f;
#pragma unroll
            for (int w = 0; w < 8; ++w) { S += redS[w * 2]; SS += redS[w * 2 + 1]; }
            int rp = (blockIdx.x & 7) * 2;
            unsafeAtomicAdd(&s2rep[rp], S);
            unsafeAtomicAdd(&s2rep[rp + 1], SS);
        }
        return;
    } else {
        // ---- gemm2 ----
#pragma unroll
        for (int rt = 0; rt < 2; ++rt)
#pragma unroll
            for (int ct = 0; ct < 4; ++ct) acc[rt][ct] = (f32x4)0.f;
#pragma unroll
        for (int kk = 0; kk < 4; ++kk) {
            short8 b[4], a[2];
#pragma unroll
            for (int ct = 0; ct < 4; ++ct)
                b[ct] = *(const short8*)(wB + ((ct * 4 + kk) << 9));
#pragma unroll
            for (int rt = 0; rt < 2; ++rt)
                a[rt] = *(const short8*)&Asb[swz(RA + rt * 16 + r16, kk * 4 + q)];
#pragma unroll
            for (int rt = 0; rt < 2; ++rt)
#pragma unroll
                for (int ct = 0; ct < 4; ++ct)
                    acc[rt][ct] = __builtin_amdgcn_mfma_f32_16x16x32_bf16(a[rt], b[ct], acc[rt][ct], 0, 0, 0);
        }
        __syncthreads();  // gemm2 LDS reads done

        float bbv[4];
#pragma unroll
        for (int ct = 0; ct < 4; ++ct) bbv[ct] = bb[CB + ct * 16 + r16];
        float s[4] = {0.f, 0.f, 0.f, 0.f}, ss[4] = {0.f, 0.f, 0.f, 0.f};
#pragma unroll
        for (int rt = 0; rt < 2; ++rt)
#pragma unroll
            for (int ct = 0; ct < 4; ++ct)
#pragma unroll
                for (int rg = 0; rg < 4; ++rg) {
                    int lr = RA + rt * 16 + q * 4 + rg;
                    int gr = row0 + lr;
                    float hv = acc[rt][ct][rg] + bbv[ct];
                    if (gr < NN) { s[ct] += hv; ss[ct] += hv * hv; }
                    Asb[swze(lr, CB + ct * 16 + r16)] = f2bf(hv);
                }
#pragma unroll
        for (int ct = 0; ct < 4; ++ct) {
            s[ct] += __shfl_xor(s[ct], 16);
            s[ct] += __shfl_xor(s[ct], 32);
            ss[ct] += __shfl_xor(ss[ct], 16);
            ss[ct] += __shfl_xor(ss[ct], 32);
        }
        if (lane < 16) {
#pragma unroll
            for (int ct = 0; ct < 4; ++ct) {
                int col = CB + ct * 16 + r16;
                redS[rh * 256 + col] = s[ct];
                redS[rh * 256 + 128 + col] = ss[ct];
            }
        }
        __syncthreads();
        if (t < 256) {
            float v = redS[t] + redS[256 + t] + redS[512 + t] + redS[768 + t];
            unsafeAtomicAdd(&statsRep[(blockIdx.x & 7) * 256 + t], v);
        }
        // coalesced bf16 store of h tile
#pragma unroll
        for (int i = 0; i < 4; ++i) {
            int f = i * 512 + t;
            int r = f >> 4, c8 = f & 15;
            int gr = row0 + r;
            if (gr < NN)
                *(short8*)(hout + (size_t)gr * 128 + c8 * 8) = *(const short8*)&Asb[swz(r, c8)];
        }
    }
}

// fused BN(1) + segment softmax(temp 5): one block per graph; graph bounds
// precomputed in k_prep (gb) — no per-block binary search.
__global__ void k_softmax(const float* __restrict__ zr, const float* __restrict__ s2rep,
                          const float* __restrict__ g2, const float* __restrict__ be2,
                          const int* __restrict__ gb, float* __restrict__ out) {
    __shared__ float rb[4];
    const int g = blockIdx.x, t = threadIdx.x;
    const int lo = gb[g], hi = gb[g + 1];
    float s = 0.f, ssq = 0.f;
#pragma unroll
    for (int i = 0; i < 8; ++i) { s += s2rep[i * 2]; ssq += s2rep[i * 2 + 1]; }
    const float mu = s / (float)NN;
    const float var = ssq / (float)NN - mu * mu;
    const float sc = g2[0] / sqrtf(var + BN_EPS) * 0.2f;
    const float sh = (be2[0] - mu * g2[0] / sqrtf(var + BN_EPS)) * 0.2f;

    float m = -INFINITY;
    for (int i = lo + t; i < hi; i += 256) m = fmaxf(m, fmaf(zr[i], sc, sh));
#pragma unroll
    for (int off = 1; off < 64; off <<= 1) m = fmaxf(m, __shfl_xor(m, off, 64));
    if ((t & 63) == 0) rb[t >> 6] = m;
    __syncthreads();
    float gmax = fmaxf(fmaxf(rb[0], rb[1]), fmaxf(rb[2], rb[3]));
    __syncthreads();

    float sum = 0.f;
    for (int i = lo + t; i < hi; i += 256) {
        float e = expf(fmaf(zr[i], sc, sh) - gmax);
        out[i] = e;
        sum += e;
    }
#pragma unroll
    for (int off = 1; off < 64; off <<= 1) sum += __shfl_xor(sum, off, 64);
    if ((t & 63) == 0) rb[t >> 6] = sum;
    __syncthreads();
    float S = rb[0] + rb[1] + rb[2] + rb[3];
    float inv = 1.0f / (S + 1e-16f);
    for (int i = lo + t; i < hi; i += 256) out[i] *= inv;
}

extern "C" void kernel_launch(void* const* d_in, const int* in_sizes, int n_in,
                              void* d_out, int out_size, void* d_ws, size_t ws_size,
                              hipStream_t stream) {
    const float* x   = (const float*)d_in[0];
    const int* ei    = (const int*)d_in[1];
    const int* batch = (const int*)d_in[2];
    const float *W0a = (const float*)d_in[3],  *b0a = (const float*)d_in[4];
    const float *W0b = (const float*)d_in[5],  *b0b = (const float*)d_in[6];
    const float *g0  = (const float*)d_in[7],  *be0 = (const float*)d_in[8];
    const float *W1a = (const float*)d_in[9],  *b1a = (const float*)d_in[10];
    const float *W1b = (const float*)d_in[11], *b1b = (const float*)d_in[12];
    const float *g1  = (const float*)d_in[13], *be1 = (const float*)d_in[14];
    const float *W2a = (const float*)d_in[15], *b2a = (const float*)d_in[16];
    const float *W2b = (const float*)d_in[17], *b2b = (const float*)d_in[18];
    const float *g2  = (const float*)d_in[19], *be2 = (const float*)d_in[20];
    float* out = (float*)d_out;

    char* wsb = (char*)d_ws;
    short* Abf = (short*)wsb;
    short* Bbf = (short*)(wsb + 25600000);
    float* Zb  = (float*)(wsb + 51200000);
    float* SMf = (float*)(wsb + 51600000);
    float* S0r = SMf;               // 8 x 256
    float* S1r = SMf + 2048;        // 8 x 256
    float* S2r = SMf + 4096;        // 8 x 2
    int* gb    = (int*)(wsb + 51616448);  // 129 graph boundaries
    int* offs  = (int*)(wsb + 51620000);
    int* bsums = (int*)(wsb + 52020004);
    int* csr   = (int*)(wsb + 52020516);
    short* Wt  = (short*)(wsb + 54580544);
    short* Xbf = (short*)(wsb + 54744384);
    // deg/pos alias Abf during CSR build
    int* deg = (int*)wsb;
    int* pos = (int*)(wsb + 400000);

    const int gE    = (EE + 255) / 256;     // 2500
    const int gGmlp = (NN + 127) / 128;     // 782

    // zero deg (stats are zeroed inside k_prep)
    (void)hipMemsetAsync(deg, 0, NN * sizeof(int), stream);

    // fused prep: x->bf16, weights->fragment order, histogram, stats zero, gb
    k_prep<<<6400, 256, 0, stream>>>(x, W0a, W0b, W1a, W1b, W2a, Wt, Xbf, ei,
                                     deg, SMf, batch, gb);

    // ---- CSR build (reused all 3 layers) ----
    k_scan1<<<NBLK, 1024, 0, stream>>>(deg, offs, bsums);
    k_scan3<<<NBLK, 1024, 0, stream>>>(offs, bsums, pos);
    k_fill<<<gE, 256, 0, stream>>>(ei, pos, csr);

    // layer 0: fused gather(Xbf) + MLP -> Abf + stats
    k_gmlp<0><<<gGmlp, 512, 0, stream>>>(Xbf, offs, csr, nullptr, nullptr, nullptr,
                                         Wt, b0a, Wt + 16384, b0b, Abf, S0r,
                                         nullptr, nullptr, nullptr, nullptr);
    // layer 1: fused gather(Abf, BN0+ReLU) + MLP -> Bbf + stats
    k_gmlp<1><<<gGmlp, 512, 0, stream>>>(Abf, offs, csr, S0r, g0, be0,
                                         Wt + 2 * 16384, b1a, Wt + 3 * 16384, b1b, Bbf, S1r,
                                         nullptr, nullptr, nullptr, nullptr);
    // layer 2: fused gather(Bbf, BN1+ReLU) + gemm1 + final dot -> Zb + s2
    k_gmlp<2><<<gGmlp, 512, 0, stream>>>(Bbf, offs, csr, S1r, g1, be1,
                                         Wt + 4 * 16384, b2a, nullptr, nullptr,
                                         nullptr, nullptr, W2b, b2b, Zb, S2r);

    // fused BN(1) + segment softmax (temperature 5)
    k_softmax<<<GG, 256, 0, stream>>>(Zb, S2r, g2, be2, gb, out);
}